// Round 23
// baseline (19.716 us; speedup 1.0000x reference)
//
#include <hip/hip_runtime.h>

#define NN 4
#define CC 128
#define HH 64
#define WW 64
#define KK 5
#define K2 25
#define HUP 128
#define WUP 128

typedef int   v4i __attribute__((ext_vector_type(4)));
typedef float v2f __attribute__((ext_vector_type(2)));

__device__ void llvm_amdgcn_raw_buffer_store_v2f32(v2f data, v4i srsrc,
                                                   int voffset, int soffset,
                                                   int aux)
    __asm("llvm.amdgcn.raw.buffer.store.v2f32");

__device__ inline v4i make_srd(const void* p, unsigned bytes) {
  union { const void* p; unsigned u[2]; } a;
  a.p = p;
  v4i r;
  r.x = (int)a.u[0];
  r.y = (int)(a.u[1] & 0xffffu);  // base[47:32], stride=0
  r.z = (int)bytes;               // num_records in bytes
  r.w = 0x00020000;               // raw dword access
  return r;
}

// DPP wave shifts (R13-proven):
//   wave_shr:1 (0x138): lane w reads w-1 (chain zeros lanes 0,1 = vj-masked).
//   wave_shl:1 (0x130): lane w reads w+1 (chain zeros lanes 62,63).
__device__ inline float dpp_prev1(float x) {  // lane w <- w-1
  return __int_as_float(__builtin_amdgcn_update_dpp(
      0, __float_as_int(x), 0x138, 0xf, 0xf, true));
}
__device__ inline float dpp_next1(float x) {  // lane w <- w+1
  return __int_as_float(__builtin_amdgcn_update_dpp(
      0, __float_as_int(x), 0x130, 0xf, 0xf, true));
}

// Pack two f32 into one u32 as 2x bf16 (round-half-up; R7-proven, masks are
// U(0,1): rel err <= 2^-9 -> output abs err ~0.04-0.06 << 0.36 threshold).
__device__ inline unsigned pack_bf16x2(float x, float y) {
  const unsigned ux = (__float_as_uint(x) + 0x8000u) >> 16;
  const unsigned uy = (__float_as_uint(y) + 0x8000u) & 0xffff0000u;
  return uy | ux;
}

// grid: NN*HH*4 = 1024 blocks, 256 threads, 52.5 KB LDS -> 3 blocks/CU
// (12 waves/CU). R23: masks transported through LDS as packed bf16x2
// (12.8 KB vs 25.6) purely to fit 3 blocks/CU at UNCHANGED 32ch
// amortization — tests whether intra-block phase serialization
// (stage->mreg->compute->store) is the ~10us non-overlap residual by
// giving each CU a 3rd block to cross-fill phases with.
// XCD chunk swizzle (R15-proven). block: cq=bid&3, h=(bid>>2)&63, n=bid>>8.
// thread: w = t&63 (output cols 2w,2w+1), wv = t>>6; c = cq*32 + ci*4 + wv.
__global__ __launch_bounds__(256) void carafe_kernel(
    const float* __restrict__ feat, const float* __restrict__ masks,
    float* __restrict__ out) {
  __shared__ float sm[10240];       // features: 32 ch x 5 rows x 64 = 40 KB
  __shared__ unsigned smm[3200];    // masks bf16x2: 25 k x 2 rows x 64 pairs

  const int orig = blockIdx.x;
  const int bid = (orig & 7) * 128 + (orig >> 3);  // XCD chunk swizzle
  const int cq = bid & 3;
  const int h  = (bid >> 2) & (HH - 1);
  const int n  = bid >> 8;
  const int t  = threadIdx.x;
  const int w  = t & (WW - 1);
  const int wv = t >> 6;  // wave id = cg

  // --- stage features: slot i = row clamp(h-2+i, 0, 63) of each channel ---
  if (h >= 2 && h <= HH - 3) {
    const int y0 = h - 2;
#pragma unroll
    for (int s = 0; s < 8; ++s) {
      const int cl = wv * 8 + s;
      const float* chg =
          feat + ((size_t)(n * CC + cq * 32 + cl) * HH + y0) * WW;
      __builtin_amdgcn_global_load_lds(
          (const __attribute__((address_space(1))) void*)(chg + w * 4),
          (__attribute__((address_space(3))) void*)(sm + cl * 320), 16, 0, 0);
      __builtin_amdgcn_global_load_lds(
          (const __attribute__((address_space(1))) void*)(chg + 256 + w),
          (__attribute__((address_space(3))) void*)(sm + cl * 320 + 256), 4, 0, 0);
    }
  } else {
    // edge: per-row clamped staging; invalid taps vi-masked.
#pragma unroll
    for (int s = 0; s < 8; ++s) {
      const int cl = wv * 8 + s;
      const float* chb = feat + (size_t)(n * CC + cq * 32 + cl) * (HH * WW);
#pragma unroll
      for (int i = 0; i < KK; ++i) {
        const int r = min(max(h - 2 + i, 0), HH - 1);
        __builtin_amdgcn_global_load_lds(
            (const __attribute__((address_space(1))) void*)(chb + r * WW + w),
            (__attribute__((address_space(3))) void*)(sm + cl * 320 + i * 64),
            4, 0, 0);
      }
    }
  }

  // --- stage masks as bf16x2: slab k = rows {2h,2h+1}; lane w packs pair
  // (2w,2w+1) of each row. Slabs k = wv+4j -> disjoint per wave. ---
#pragma unroll
  for (int j = 0; j < 7; ++j) {
    const int k = wv + 4 * j;
    if (k < K2) {
      const float* mg = masks + (((size_t)n * K2 + k) * HUP + 2 * h) * WUP;
      const float2 g0 = *reinterpret_cast<const float2*>(&mg[2 * w]);
      const float2 g1 = *reinterpret_cast<const float2*>(&mg[WUP + 2 * w]);
      smm[k * 128 + w]      = pack_bf16x2(g0.x, g0.y);
      smm[k * 128 + 64 + w] = pack_bf16x2(g1.x, g1.y);
    }
  }

  // --- validity (VALU, overlaps staging latency) ---
  float vi[KK], vj[KK];
#pragma unroll
  for (int i = 0; i < KK; ++i) {
    const int r = h - 2 + i;
    vi[i] = (r >= 0 && r < HH) ? 1.f : 0.f;
    const int x = w - 2 + i;
    vj[i] = (x >= 0 && x < WW) ? 1.f : 0.f;
  }

  const v4i srdO = make_srd(out, (unsigned)(NN * CC * HUP * WUP) * 4u);
  int vob = (((n * CC + cq * 32 + wv) * HUP + 2 * h) * WUP + 2 * w) * 4;

  __syncthreads();  // staging complete (drains vmcnt + lgkmcnt)

  // --- mreg from LDS: unpack bf16x2 pair, scale by validity ---
  v2f mreg[K2][2];
#pragma unroll
  for (int k = 0; k < K2; ++k) {
    const int i = k / KK, j = k % KK;
    const float vv = vi[i] * vj[j];
    const unsigned u0 = smm[k * 128 + w];
    const unsigned u1 = smm[k * 128 + 64 + w];
    v2f m0, m1;
    m0.x = __uint_as_float(u0 << 16);
    m0.y = __uint_as_float(u0 & 0xffff0000u);
    m1.x = __uint_as_float(u1 << 16);
    m1.y = __uint_as_float(u1 & 0xffff0000u);
    mreg[k][0] = m0 * vv;
    mreg[k][1] = m1 * vv;
  }

  // Even/odd accumulator split (R21).
#define FA(k, e)                                                         \
  do {                                                                   \
    v2f ff; ff.x = (e); ff.y = (e);                                      \
    acc0a += ff * mreg[k][0]; acc1a += ff * mreg[k][1];                  \
  } while (0)
#define FB(k, e)                                                         \
  do {                                                                   \
    v2f ff; ff.x = (e); ff.y = (e);                                      \
    acc0b += ff * mreg[k][0]; acc1b += ff * mreg[k][1];                  \
  } while (0)

  // --- compute: 8 channels/thread; taps r -> m1/p1 -> m2/p2; unroll 4 ---
  int cbase = wv * 320 + w;  // dword base of this thread's channel slot
#pragma unroll 4
  for (int ci = 0; ci < 8; ++ci) {
    v2f acc0a = {0.f, 0.f}, acc1a = {0.f, 0.f};
    v2f acc0b = {0.f, 0.f}, acc1b = {0.f, 0.f};
#pragma unroll
    for (int i = 0; i < KK; ++i) {
      const float r  = sm[cbase + i * 64];  // lane w -> element w of slot i
      const float m1 = dpp_prev1(r);        // x = w-1
      const float p1 = dpp_next1(r);        // x = w+1
      const float m2 = dpp_prev1(m1);       // x = w-2
      const float p2 = dpp_next1(p1);       // x = w+2
      FA(i * KK + 2, r);
      FB(i * KK + 1, m1);
      FA(i * KK + 3, p1);
      FB(i * KK + 0, m2);
      FA(i * KK + 4, p2);
    }
    const v2f acc0 = acc0a + acc0b;
    const v2f acc1 = acc1a + acc1b;
    llvm_amdgcn_raw_buffer_store_v2f32(acc0, srdO, vob, 0, 0);
    llvm_amdgcn_raw_buffer_store_v2f32(acc1, srdO, vob + WUP * 4, 0, 0);

    cbase += 4 * 320;            // +4 channels (cg-interleaved)
    vob += 4 * HUP * WUP * 4;
  }
#undef FA
#undef FB
}

extern "C" void kernel_launch(void* const* d_in, const int* in_sizes, int n_in,
                              void* d_out, int out_size, void* d_ws, size_t ws_size,
                              hipStream_t stream) {
  const float* feat  = (const float*)d_in[0];
  const float* masks = (const float*)d_in[1];
  float* out = (float*)d_out;
  (void)in_sizes; (void)n_in; (void)out_size; (void)d_ws; (void)ws_size;
  carafe_kernel<<<NN * HH * 4, 256, 0, stream>>>(feat, masks, out);
}

// Round 24
// 17.980 us; speedup vs baseline: 1.0965x; 1.0965x over previous
//
#include <hip/hip_runtime.h>

#define NN 4
#define CC 128
#define HH 64
#define WW 64
#define KK 5
#define K2 25
#define HUP 128
#define WUP 128

typedef int   v4i __attribute__((ext_vector_type(4)));
typedef float v2f __attribute__((ext_vector_type(2)));

__device__ void llvm_amdgcn_raw_buffer_store_v2f32(v2f data, v4i srsrc,
                                                   int voffset, int soffset,
                                                   int aux)
    __asm("llvm.amdgcn.raw.buffer.store.v2f32");

__device__ inline v4i make_srd(const void* p, unsigned bytes) {
  union { const void* p; unsigned u[2]; } a;
  a.p = p;
  v4i r;
  r.x = (int)a.u[0];
  r.y = (int)(a.u[1] & 0xffffu);  // base[47:32], stride=0
  r.z = (int)bytes;               // num_records in bytes
  r.w = 0x00020000;               // raw dword access
  return r;
}

// DPP wave shifts (R13-proven):
//   wave_shr:1 (0x138): lane w reads w-1 (chain zeros lanes 0,1 = vj-masked).
//   wave_shl:1 (0x130): lane w reads w+1 (chain zeros lanes 62,63).
__device__ inline float dpp_prev1(float x) {  // lane w <- w-1
  return __int_as_float(__builtin_amdgcn_update_dpp(
      0, __float_as_int(x), 0x138, 0xf, 0xf, true));
}
__device__ inline float dpp_next1(float x) {  // lane w <- w+1
  return __int_as_float(__builtin_amdgcn_update_dpp(
      0, __float_as_int(x), 0x130, 0xf, 0xf, true));
}

// grid: NN*HH*4 = 1024 blocks, 256 threads, 66.5 KB LDS -> 2 blocks/CU.
// XCD chunk swizzle. block: cq=bid&3, h=(bid>>2)&63, n=bid>>8.
// thread: w = t&63 (output cols 2w,2w+1), wv = t>>6; c = cq*32 + ci*4 + wv.
//
// FINAL (session best, R17): single global->LDS staging exposure
// (features: slot i = pre-clamped tap row -> static offsets i*64;
// masks: 25 cooperative 1KB-slab global_load_lds), LDS-fed compute loop
// with 1 ds_read + 4 DPP wave-shifts per window row, validity folded
// into mask registers, buffer v2f stores.
__global__ __launch_bounds__(256) void carafe_kernel(
    const float* __restrict__ feat, const float* __restrict__ masks,
    float* __restrict__ out) {
  __shared__ float sm[10240];   // features: 32 ch x 5 rows x 64 = 40 KB
  __shared__ float smm[6400];   // masks: 25 k x 2 rows x 128 wup = 25.6 KB

  const int orig = blockIdx.x;
  const int bid = (orig & 7) * 128 + (orig >> 3);  // XCD chunk swizzle
  const int cq = bid & 3;
  const int h  = (bid >> 2) & (HH - 1);
  const int n  = bid >> 8;
  const int t  = threadIdx.x;
  const int w  = t & (WW - 1);
  const int wv = t >> 6;  // wave id = cg

  // --- stage features: slot i = row clamp(h-2+i, 0, 63) of each channel ---
  if (h >= 2 && h <= HH - 3) {
    // interior: rows h-2..h+2 contiguous -> width16 (rows 0..3) + width4
    const int y0 = h - 2;
#pragma unroll
    for (int s = 0; s < 8; ++s) {
      const int cl = wv * 8 + s;
      const float* chg =
          feat + ((size_t)(n * CC + cq * 32 + cl) * HH + y0) * WW;
      __builtin_amdgcn_global_load_lds(
          (const __attribute__((address_space(1))) void*)(chg + w * 4),
          (__attribute__((address_space(3))) void*)(sm + cl * 320), 16, 0, 0);
      __builtin_amdgcn_global_load_lds(
          (const __attribute__((address_space(1))) void*)(chg + 256 + w),
          (__attribute__((address_space(3))) void*)(sm + cl * 320 + 256), 4, 0, 0);
    }
  } else {
    // edge: per-row clamped staging (slot i <- row clamp(h-2+i,0,63));
    // invalid taps are vi-masked, duplicated rows harmless.
#pragma unroll
    for (int s = 0; s < 8; ++s) {
      const int cl = wv * 8 + s;
      const float* chb = feat + (size_t)(n * CC + cq * 32 + cl) * (HH * WW);
#pragma unroll
      for (int i = 0; i < KK; ++i) {
        const int r = min(max(h - 2 + i, 0), HH - 1);
        __builtin_amdgcn_global_load_lds(
            (const __attribute__((address_space(1))) void*)(chb + r * WW + w),
            (__attribute__((address_space(3))) void*)(sm + cl * 320 + i * 64),
            4, 0, 0);
      }
    }
  }

  // --- stage masks: per k one 1KB slab masks[n,k,2h:2h+2,:] -> smm[k] ---
#pragma unroll
  for (int j = 0; j < 7; ++j) {
    const int k = wv + 4 * j;
    if (k < K2) {
      const float* mg = masks + (((size_t)n * K2 + k) * HUP + 2 * h) * WUP;
      __builtin_amdgcn_global_load_lds(
          (const __attribute__((address_space(1))) void*)(mg + w * 4),
          (__attribute__((address_space(3))) void*)(smm + k * 256), 16, 0, 0);
    }
  }

  // --- validity (VALU, overlaps staging latency) ---
  float vi[KK], vj[KK];
#pragma unroll
  for (int i = 0; i < KK; ++i) {
    const int r = h - 2 + i;
    vi[i] = (r >= 0 && r < HH) ? 1.f : 0.f;
    const int x = w - 2 + i;
    vj[i] = (x >= 0 && x < WW) ? 1.f : 0.f;
  }

  const v4i srdO = make_srd(out, (unsigned)(NN * CC * HUP * WUP) * 4u);
  int vob = (((n * CC + cq * 32 + wv) * HUP + 2 * h) * WUP + 2 * w) * 4;

  __syncthreads();  // all staging complete

  // --- mreg from LDS: smm[k*256 + a*128 + 2w..2w+1] * vv ---
  v2f mreg[K2][2];
#pragma unroll
  for (int k = 0; k < K2; ++k) {
    const int i = k / KK, j = k % KK;
    const float vv = vi[i] * vj[j];
    const v2f u0 = *reinterpret_cast<const v2f*>(&smm[k * 256 + 2 * w]);
    const v2f u1 = *reinterpret_cast<const v2f*>(&smm[k * 256 + 128 + 2 * w]);
    mreg[k][0] = u0 * vv;
    mreg[k][1] = u1 * vv;
  }

#define FMA1(k, e)                                                       \
  do {                                                                   \
    v2f ff; ff.x = (e); ff.y = (e);                                      \
    acc0 += ff * mreg[k][0]; acc1 += ff * mreg[k][1];                    \
  } while (0)

  // --- compute: 8 channels/thread; static tap offsets i*64 ->
  // 2x ds_read2_b32 + 1x ds_read_b32 per row-set; unroll 2 for overlap ---
  int cbase = wv * 320 + w;  // dword base of this thread's channel slot
#pragma unroll 2
  for (int ci = 0; ci < 8; ++ci) {
    v2f acc0 = {0.f, 0.f}, acc1 = {0.f, 0.f};
#pragma unroll
    for (int i = 0; i < KK; ++i) {
      const float r  = sm[cbase + i * 64];  // lane w -> element w of slot i
      const float m1 = dpp_prev1(r);        // x = w-1
      const float m2 = dpp_prev1(m1);       // x = w-2
      const float p1 = dpp_next1(r);        // x = w+1
      const float p2 = dpp_next1(p1);       // x = w+2
      FMA1(i * KK + 0, m2);
      FMA1(i * KK + 1, m1);
      FMA1(i * KK + 2, r);
      FMA1(i * KK + 3, p1);
      FMA1(i * KK + 4, p2);
    }
    llvm_amdgcn_raw_buffer_store_v2f32(acc0, srdO, vob, 0, 0);
    llvm_amdgcn_raw_buffer_store_v2f32(acc1, srdO, vob + WUP * 4, 0, 0);

    cbase += 4 * 320;            // +4 channels (cg-interleaved)
    vob += 4 * HUP * WUP * 4;
  }
#undef FMA1
}

extern "C" void kernel_launch(void* const* d_in, const int* in_sizes, int n_in,
                              void* d_out, int out_size, void* d_ws, size_t ws_size,
                              hipStream_t stream) {
  const float* feat  = (const float*)d_in[0];
  const float* masks = (const float*)d_in[1];
  float* out = (float*)d_out;
  (void)in_sizes; (void)n_in; (void)out_size; (void)d_ws; (void)ws_size;
  carafe_kernel<<<NN * HH * 4, 256, 0, stream>>>(feat, masks, out);
}